// Round 6
// baseline (407.866 us; speedup 1.0000x reference)
//
#include <hip/hip_runtime.h>
#include <hip/hip_bf16.h>
#include <stdint.h>

#define DM 2048
#define NH 16
#define HD 128
#define NB 2
#define SQ 2048

typedef __bf16 bf16x8 __attribute__((ext_vector_type(8)));
typedef float f32x4 __attribute__((ext_vector_type(4)));

typedef __attribute__((address_space(1))) uint32_t as1_u32;
typedef __attribute__((address_space(3))) uint32_t as3_u32;

__device__ __forceinline__ void gload16(const void* g, void* l) {
  __builtin_amdgcn_global_load_lds((const as1_u32*)g, (as3_u32*)l, 16, 0, 0);
}

__device__ __forceinline__ unsigned short f2bf(float f) {
  __hip_bfloat16 h = __float2bfloat16(f);
  return __builtin_bit_cast(unsigned short, h);
}

// LDS bank swizzle for the P scratch: 16B-slot XOR for row r.
__device__ __forceinline__ int swz(int r) { return (r ^ (r >> 3)) & 7; }

__global__ void cast_f32_to_bf16(const float* __restrict__ in,
                                 unsigned short* __restrict__ out, int n) {
  int stride = gridDim.x * blockDim.x * 4;
  for (int i = (blockIdx.x * blockDim.x + threadIdx.x) * 4; i < n; i += stride) {
    float4 v = *reinterpret_cast<const float4*>(in + i);
    ushort4 o;
    o.x = f2bf(v.x); o.y = f2bf(v.y); o.z = f2bf(v.z); o.w = f2bf(v.w);
    *reinterpret_cast<ushort4*>(out + i) = o;
  }
}

// Wq (2048x2048) -> Wqkvb rows 0..2047; Wkv (256x2048) -> rows 2048..2303;
// Wo (2048x2048) -> Wob. All contiguous segments.
__global__ void cast_weights(const float* __restrict__ Wq,
                             const float* __restrict__ Wkv,
                             const float* __restrict__ Wo,
                             unsigned short* __restrict__ Wqkvb,
                             unsigned short* __restrict__ Wob) {
  const int n = 4194304 + 524288 + 4194304;
  int stride = gridDim.x * blockDim.x * 4;
  for (int i = (blockIdx.x * blockDim.x + threadIdx.x) * 4; i < n; i += stride) {
    const float* src; unsigned short* dst;
    if (i < 4194304)      { src = Wq + i;            dst = Wqkvb + i; }
    else if (i < 4718592) { src = Wkv + (i - 4194304); dst = Wqkvb + i; }
    else                  { src = Wo + (i - 4718592);  dst = Wob + (i - 4718592); }
    float4 v = *reinterpret_cast<const float4*>(src);
    ushort4 o;
    o.x = f2bf(v.x); o.y = f2bf(v.y); o.z = f2bf(v.z); o.w = f2bf(v.w);
    *reinterpret_cast<ushort4*>(dst) = o;
  }
}

// C = A * B^T. A: M x K bf16 row-major. B: N x K bf16 row-major.
// MODE 1: f32 out (C0, row stride N).
// MODE 2: fused QKV epilogue (N=2304, column-block-aligned routing):
//   cc < 2048          -> Qb[m*2048+cc] = v*scale (bf16)   [scale = log2e/sqrt(HD)]
//   2048 <= cc < 2176  -> Kc[m*128 + cc-2048]
//   cc >= 2176         -> Vt[(b*128 + cc-2176)*2048 + sigma-permuted s]
//   (sigma(c) = (c&15)*8 + (c>>4) within each 128-tile of s; PV is invariant
//    under a shared kv-permutation of P-cols and V-rows.)
template<int MODE>
__global__ void gemm_bt(const unsigned short* __restrict__ A,
                        const unsigned short* __restrict__ Bm,
                        void* __restrict__ C0, void* __restrict__ C1,
                        void* __restrict__ C2,
                        int M, int N, int K, float scale) {
  __shared__ unsigned short As[128 * 32];
  __shared__ unsigned short Bs[128 * 32];
  const int t = threadIdx.x;
  const int w = t >> 6, l = t & 63;
  const int lr = l & 15, lkb = (l >> 4) * 8;
  const int m0 = blockIdx.x * 128, n0 = blockIdx.y * 128;
  const int wr = (w >> 1) * 64, wc = (w & 1) * 64;
  f32x4 acc[4][4] = {};
  for (int k0 = 0; k0 < K; k0 += 32) {
#pragma unroll
    for (int p = 0; p < 2; ++p) {
      int seg = p * 256 + t;
      int row = seg >> 2, c8 = (seg & 3) * 8;
      gload16(A + (size_t)(m0 + row) * K + k0 + c8, (void*)(As + seg * 8));
      gload16(Bm + (size_t)(n0 + row) * K + k0 + c8, (void*)(Bs + seg * 8));
    }
    __syncthreads();
    bf16x8 af[4], bfv[4];
#pragma unroll
    for (int mi = 0; mi < 4; ++mi)
      af[mi] = *reinterpret_cast<const bf16x8*>(As + (wr + mi * 16 + lr) * 32 + lkb);
#pragma unroll
    for (int ni = 0; ni < 4; ++ni)
      bfv[ni] = *reinterpret_cast<const bf16x8*>(Bs + (wc + ni * 16 + lr) * 32 + lkb);
#pragma unroll
    for (int mi = 0; mi < 4; ++mi)
#pragma unroll
      for (int ni = 0; ni < 4; ++ni)
        acc[mi][ni] = __builtin_amdgcn_mfma_f32_16x16x32_bf16(af[mi], bfv[ni], acc[mi][ni], 0, 0, 0);
    __syncthreads();
  }
#pragma unroll
  for (int mi = 0; mi < 4; ++mi) {
#pragma unroll
    for (int ni = 0; ni < 4; ++ni) {
      const int r0 = m0 + wr + mi * 16 + (l >> 4) * 4;
      const int cc = n0 + wc + ni * 16 + lr;
#pragma unroll
      for (int j = 0; j < 4; ++j) {
        float v = acc[mi][ni][j];
        if (MODE == 1) {
          ((float*)C0)[(size_t)(r0 + j) * N + cc] = v;
        } else {
          int m = r0 + j;
          if (cc < DM) {
            ((unsigned short*)C0)[(size_t)m * DM + cc] = f2bf(v * scale);
          } else if (cc < DM + HD) {
            ((unsigned short*)C1)[(size_t)m * HD + (cc - DM)] = f2bf(v);
          } else {
            int b = m >> 11, s = m & (SQ - 1);
            int c = s & 127;
            int sp = (s & ~127) + ((c & 15) * 8 + (c >> 4));
            ((unsigned short*)C2)[((size_t)b * HD + (cc - DM - HD)) * SQ + sp] = f2bf(v);
          }
        }
      }
    }
  }
}

// Flash attention, MQA — barrier-free. Qb: [4096][2048] bf16, pre-scaled by
// log2e/sqrt(128) (softmax done in exp2 domain). Kc: [b][s][128] bf16.
// Vt: [b][d][sigma(s)] bf16. Hb out: [b][s][h*128+d] bf16.
// K/V fragments are read DIRECTLY from global (L2-resident: 1MB per batch,
// shared by 256 blocks) — no LDS staging, no __syncthreads anywhere.
// Each wave owns 32 q-rows and a private 8KB LDS region used only for the
// P round-trip (C-fragment -> A-fragment), sigma-packed b128 writes.
// NOTE: no PV k-slice skip on the diagonal — sigma scatters P's zero columns
// across ALL k-slices, so a slice-level skip is incorrect (round-5 bug).
// Grid: 1D 512; id and id+256 carry complementary qt for CU load balance.
__global__ __launch_bounds__(256) void mqa_attn(const unsigned short* __restrict__ Qb,
                                                const unsigned short* __restrict__ Kc,
                                                const unsigned short* __restrict__ Vt,
                                                unsigned short* __restrict__ Hb) {
  __shared__ unsigned short Ps_all[4 * 32 * 128];  // 32KB: per-wave P scratch
  const int t = threadIdx.x, w = t >> 6, l = t & 63;
  const int lr = l & 15, hi = l >> 4;
  const int lkb = hi * 8;
  const int id = blockIdx.x;
  const int pp = id & 255;
  const int bh = pp >> 3, k8 = pp & 7;
  const int qt = (id < 256) ? (15 - k8) : k8;
  const int b = bh >> 4, h = bh & 15;
  const int q0 = qt * 128;
  unsigned short* Ps = Ps_all + w * 32 * 128;

  bf16x8 qf[2][4];
#pragma unroll
  for (int mi = 0; mi < 2; ++mi)
#pragma unroll
    for (int kk = 0; kk < 4; ++kk) {
      const uint4* p = reinterpret_cast<const uint4*>(
          Qb + (size_t)(b * SQ + q0 + w * 32 + mi * 16 + lr) * DM + h * HD + kk * 32 + lkb);
      qf[mi][kk] = __builtin_bit_cast(bf16x8, *p);
    }
  f32x4 o[2][8] = {};
  float mrun[2][4], lrun[2][4];
#pragma unroll
  for (int mi = 0; mi < 2; ++mi)
#pragma unroll
    for (int j = 0; j < 4; ++j) { mrun[mi][j] = -3.0e38f; lrun[mi][j] = 0.f; }

  for (int kt = 0; kt <= qt; ++kt) {
    const bool diag = (kt == qt);
    const int nlim = diag ? 2 * w + 2 : 8;  // QK frags fully above diagonal skipped
    const unsigned short* Kg = Kc + (size_t)(b * SQ + kt * 128) * HD;
    const unsigned short* Vg = Vt + (size_t)b * HD * SQ + kt * 128;

    f32x4 s[2][8] = {};
#pragma unroll
    for (int kk = 0; kk < 4; ++kk) {
      bf16x8 kf[8];
#pragma unroll
      for (int ni = 0; ni < 8; ++ni)
        if (ni < nlim)
          kf[ni] = __builtin_bit_cast(bf16x8, *reinterpret_cast<const uint4*>(
              Kg + (size_t)(ni * 16 + lr) * HD + kk * 32 + lkb));
#pragma unroll
      for (int mi = 0; mi < 2; ++mi)
#pragma unroll
        for (int ni = 0; ni < 8; ++ni)
          if (ni < nlim)
            s[mi][ni] = __builtin_amdgcn_mfma_f32_16x16x32_bf16(qf[mi][kk], kf[ni], s[mi][ni], 0, 0, 0);
    }

    if (diag) {  // causal mask (also overwrites the skipped garbage frags)
#pragma unroll
      for (int mi = 0; mi < 2; ++mi)
#pragma unroll
        for (int ni = 0; ni < 8; ++ni)
#pragma unroll
          for (int j = 0; j < 4; ++j) {
            int rq = w * 32 + mi * 16 + hi * 4 + j;
            int ck = ni * 16 + lr;
            if (ck > rq) s[mi][ni][j] = -3.0e38f;
          }
    }

#pragma unroll
    for (int mi = 0; mi < 2; ++mi) {
#pragma unroll
      for (int j = 0; j < 4; ++j) {
        float pm = s[mi][0][j];
#pragma unroll
        for (int ni = 1; ni < 8; ++ni) pm = fmaxf(pm, s[mi][ni][j]);
#pragma unroll
        for (int dd = 1; dd < 16; dd <<= 1) pm = fmaxf(pm, __shfl_xor(pm, dd));
        if (pm > mrun[mi][j]) {  // exact rescale-skip
          float sc = __builtin_amdgcn_exp2f(mrun[mi][j] - pm);
          mrun[mi][j] = pm;
          lrun[mi][j] *= sc;
#pragma unroll
          for (int ni = 0; ni < 8; ++ni) o[mi][ni][j] *= sc;
        }
        float mnew = mrun[mi][j];
        float rs = 0.f;
#pragma unroll
        for (int ni = 0; ni < 8; ++ni) {
          float pv = __builtin_amdgcn_exp2f(s[mi][ni][j] - mnew);
          s[mi][ni][j] = pv;
          rs += pv;
        }
#pragma unroll
        for (int dd = 1; dd < 16; dd <<= 1) rs += __shfl_xor(rs, dd);
        lrun[mi][j] += rs;
      }
    }

    // P -> per-wave LDS, sigma-packed: value at natural kv-col ni*16+lr goes
    // to position lr*8+ni, so each (mi,j) row is one b128 write (slot lr).
#pragma unroll
    for (int mi = 0; mi < 2; ++mi)
#pragma unroll
      for (int j = 0; j < 4; ++j) {
        int prow = mi * 16 + hi * 4 + j;
        unsigned short pk[8];
#pragma unroll
        for (int ni = 0; ni < 8; ++ni) pk[ni] = f2bf(s[mi][ni][j]);
        *reinterpret_cast<uint4*>(Ps + prow * 128 + ((lr ^ swz(prow)) << 3)) =
            *reinterpret_cast<const uint4*>(pk);
      }

#pragma unroll
    for (int kk = 0; kk < 4; ++kk) {
      bf16x8 pa[2], vf[8];
#pragma unroll
      for (int ni = 0; ni < 8; ++ni)
        vf[ni] = __builtin_bit_cast(bf16x8, *reinterpret_cast<const uint4*>(
            Vg + (size_t)(ni * 16 + lr) * SQ + kk * 32 + lkb));
#pragma unroll
      for (int mi = 0; mi < 2; ++mi) {
        int r = mi * 16 + lr;
        pa[mi] = *reinterpret_cast<const bf16x8*>(
            Ps + r * 128 + (((kk * 4 + hi) ^ swz(r)) << 3));
      }
#pragma unroll
      for (int mi = 0; mi < 2; ++mi)
#pragma unroll
        for (int ni = 0; ni < 8; ++ni)
          o[mi][ni] = __builtin_amdgcn_mfma_f32_16x16x32_bf16(pa[mi], vf[ni], o[mi][ni], 0, 0, 0);
    }
  }

#pragma unroll
  for (int mi = 0; mi < 2; ++mi)
#pragma unroll
    for (int ni = 0; ni < 8; ++ni)
#pragma unroll
      for (int j = 0; j < 4; ++j) {
        int q = q0 + w * 32 + mi * 16 + hi * 4 + j;
        float val = o[mi][ni][j] / lrun[mi][j];
        Hb[(size_t)(b * SQ + q) * DM + h * HD + ni * 16 + lr] = f2bf(val);
      }
}

extern "C" void kernel_launch(void* const* d_in, const int* in_sizes, int n_in,
                              void* d_out, int out_size, void* d_ws, size_t ws_size,
                              hipStream_t stream) {
  const float* X   = (const float*)d_in[0];
  const float* Wq  = (const float*)d_in[1];
  const float* Wkv = (const float*)d_in[2];
  const float* Wo  = (const float*)d_in[3];
  char* ws = (char*)d_ws;
  // ws layout (bytes)
  unsigned short* Xb    = (unsigned short*)(ws + 0);           // 16 MB
  unsigned short* Wqkvb = (unsigned short*)(ws + 16777216);    // 9 MB [2304][2048]
  unsigned short* Wob   = (unsigned short*)(ws + 26214400);    // 8 MB
  unsigned short* Qb    = (unsigned short*)(ws + 34603008);    // 16 MB
  unsigned short* Kc    = (unsigned short*)(ws + 51380224);    // 1 MB
  unsigned short* Vt    = (unsigned short*)(ws + 52428800);    // 1 MB
  unsigned short* Hb    = (unsigned short*)(ws + 53477376);    // 16 MB

  cast_f32_to_bf16<<<2048, 256, 0, stream>>>(X, Xb, NB * SQ * DM);
  cast_weights<<<2048, 256, 0, stream>>>(Wq, Wkv, Wo, Wqkvb, Wob);

  // [Q | K | V] = X [Wq;Wkv]^T fused: Q scaled by log2e/sqrt(HD) -> Qb,
  // K -> Kc [b][s][128], V -> Vt [b][d][sigma(s)]
  gemm_bt<2><<<dim3(32, 18), 256, 0, stream>>>(Xb, Wqkvb, Qb, Kc, Vt,
                                               NB * SQ, DM + 2 * HD, DM,
                                               0.1275174293f);
  // attention -> Hb [b][s][h*128+d]
  mqa_attn<<<512, 256, 0, stream>>>(Qb, Kc, Vt, Hb);
  // out = Hb Wo^T, f32
  gemm_bt<1><<<dim3(32, 16), 256, 0, stream>>>(Hb, Wob, d_out, nullptr, nullptr,
                                               NB * SQ, DM, DM, 1.0f);
}

// Round 9
// 339.838 us; speedup vs baseline: 1.2002x; 1.2002x over previous
//
#include <hip/hip_runtime.h>
#include <hip/hip_bf16.h>
#include <stdint.h>

#define DM 2048
#define NH 16
#define HD 128
#define NB 2
#define SQ 2048

typedef __bf16 bf16x8 __attribute__((ext_vector_type(8)));
typedef float f32x4 __attribute__((ext_vector_type(4)));

typedef __attribute__((address_space(1))) uint32_t as1_u32;
typedef __attribute__((address_space(3))) uint32_t as3_u32;

__device__ __forceinline__ void gload16(const void* g, void* l) {
  __builtin_amdgcn_global_load_lds((const as1_u32*)g, (as3_u32*)l, 16, 0, 0);
}

__device__ __forceinline__ unsigned short f2bf(float f) {
  __hip_bfloat16 h = __float2bfloat16(f);
  return __builtin_bit_cast(unsigned short, h);
}

// LDS bank swizzle: 16B-slot XOR for row r.
__device__ __forceinline__ int swz(int r) { return (r ^ (r >> 3)) & 7; }

__global__ void cast_f32_to_bf16(const float* __restrict__ in,
                                 unsigned short* __restrict__ out, int n) {
  int stride = gridDim.x * blockDim.x * 4;
  for (int i = (blockIdx.x * blockDim.x + threadIdx.x) * 4; i < n; i += stride) {
    float4 v = *reinterpret_cast<const float4*>(in + i);
    ushort4 o;
    o.x = f2bf(v.x); o.y = f2bf(v.y); o.z = f2bf(v.z); o.w = f2bf(v.w);
    *reinterpret_cast<ushort4*>(out + i) = o;
  }
}

// Wq (2048x2048) -> Wqkvb rows 0..2047; Wkv (256x2048) -> rows 2048..2303;
// Wo (2048x2048) -> Wob. All contiguous segments.
__global__ void cast_weights(const float* __restrict__ Wq,
                             const float* __restrict__ Wkv,
                             const float* __restrict__ Wo,
                             unsigned short* __restrict__ Wqkvb,
                             unsigned short* __restrict__ Wob) {
  const int n = 4194304 + 524288 + 4194304;
  int stride = gridDim.x * blockDim.x * 4;
  for (int i = (blockIdx.x * blockDim.x + threadIdx.x) * 4; i < n; i += stride) {
    const float* src; unsigned short* dst;
    if (i < 4194304)      { src = Wq + i;            dst = Wqkvb + i; }
    else if (i < 4718592) { src = Wkv + (i - 4194304); dst = Wqkvb + i; }
    else                  { src = Wo + (i - 4718592);  dst = Wob + (i - 4718592); }
    float4 v = *reinterpret_cast<const float4*>(src);
    ushort4 o;
    o.x = f2bf(v.x); o.y = f2bf(v.y); o.z = f2bf(v.z); o.w = f2bf(v.w);
    *reinterpret_cast<ushort4*>(dst) = o;
  }
}

// C = A * B^T. A: M x K bf16 row-major. B: N x K bf16 row-major.
// MODE 1: f32 out (C0, row stride N).
// MODE 2: fused QKV epilogue (N=2304, column-block-aligned routing):
//   cc < 2048          -> Qb[m*2048+cc] = v*scale (bf16)   [scale = log2e/sqrt(HD)]
//   2048 <= cc < 2176  -> Kc[m*128 + cc-2048]
//   cc >= 2176         -> Vt[(b*128 + cc-2176)*2048 + sigma-permuted s]
//   (sigma(c) = (c&15)*8 + (c>>4) within each 128-tile of s; PV is invariant
//    under a shared kv-permutation of P-cols and V-rows.)
template<int MODE>
__global__ void gemm_bt(const unsigned short* __restrict__ A,
                        const unsigned short* __restrict__ Bm,
                        void* __restrict__ C0, void* __restrict__ C1,
                        void* __restrict__ C2,
                        int M, int N, int K, float scale) {
  __shared__ unsigned short As[128 * 32];
  __shared__ unsigned short Bs[128 * 32];
  const int t = threadIdx.x;
  const int w = t >> 6, l = t & 63;
  const int lr = l & 15, lkb = (l >> 4) * 8;
  const int m0 = blockIdx.x * 128, n0 = blockIdx.y * 128;
  const int wr = (w >> 1) * 64, wc = (w & 1) * 64;
  f32x4 acc[4][4] = {};
  for (int k0 = 0; k0 < K; k0 += 32) {
#pragma unroll
    for (int p = 0; p < 2; ++p) {
      int seg = p * 256 + t;
      int row = seg >> 2, c8 = (seg & 3) * 8;
      gload16(A + (size_t)(m0 + row) * K + k0 + c8, (void*)(As + seg * 8));
      gload16(Bm + (size_t)(n0 + row) * K + k0 + c8, (void*)(Bs + seg * 8));
    }
    __syncthreads();
    bf16x8 af[4], bfv[4];
#pragma unroll
    for (int mi = 0; mi < 4; ++mi)
      af[mi] = *reinterpret_cast<const bf16x8*>(As + (wr + mi * 16 + lr) * 32 + lkb);
#pragma unroll
    for (int ni = 0; ni < 4; ++ni)
      bfv[ni] = *reinterpret_cast<const bf16x8*>(Bs + (wc + ni * 16 + lr) * 32 + lkb);
#pragma unroll
    for (int mi = 0; mi < 4; ++mi)
#pragma unroll
      for (int ni = 0; ni < 4; ++ni)
        acc[mi][ni] = __builtin_amdgcn_mfma_f32_16x16x32_bf16(af[mi], bfv[ni], acc[mi][ni], 0, 0, 0);
    __syncthreads();
  }
#pragma unroll
  for (int mi = 0; mi < 4; ++mi) {
#pragma unroll
    for (int ni = 0; ni < 4; ++ni) {
      const int r0 = m0 + wr + mi * 16 + (l >> 4) * 4;
      const int cc = n0 + wc + ni * 16 + lr;
#pragma unroll
      for (int j = 0; j < 4; ++j) {
        float v = acc[mi][ni][j];
        if (MODE == 1) {
          ((float*)C0)[(size_t)(r0 + j) * N + cc] = v;
        } else {
          int m = r0 + j;
          if (cc < DM) {
            ((unsigned short*)C0)[(size_t)m * DM + cc] = f2bf(v * scale);
          } else if (cc < DM + HD) {
            ((unsigned short*)C1)[(size_t)m * HD + (cc - DM)] = f2bf(v);
          } else {
            int b = m >> 11, s = m & (SQ - 1);
            int c = s & 127;
            int sp = (s & ~127) + ((c & 15) * 8 + (c >> 4));
            ((unsigned short*)C2)[((size_t)b * HD + (cc - DM - HD)) * SQ + sp] = f2bf(v);
          }
        }
      }
    }
  }
}

// Flash attention, MQA. Qb: [4096][2048] bf16, pre-scaled by log2e/sqrt(128)
// (softmax in exp2 domain). Kc: [b][s][128] bf16. Vt: [b][d][sigma(s)] bf16.
// Hb out: [b][s][h*128+d] bf16.
// Block: 256 thr (4 waves x 32 q-rows). KV tile = 128, STAGED in LDS via
// global_load_lds (round-6 lesson: direct-from-L2 fragment reads are
// latency-bound at 8 waves/CU — staging bulk-issues the loads and converts
// all consumer reads to LDS). 16B slots XOR-swizzled with swz(row), staged
// via pre-swizzled GLOBAL source column (both-sides involution).
// P overlays the K region per-wave after the QK barrier, sigma-packed b128.
// Diagonal QK frag skip (nlim): frags fully above the diagonal are skipped
// and overwritten by the mask. No PV k-slice skip (sigma scatters zeros
// across all slices — round-5 bug).
// Grid: 1D 512; id and id+256 carry complementary qt for CU load balance.
__global__ __launch_bounds__(256) void mqa_attn(const unsigned short* __restrict__ Qb,
                                                const unsigned short* __restrict__ Kc,
                                                const unsigned short* __restrict__ Vt,
                                                unsigned short* __restrict__ Hb) {
  __shared__ unsigned short Ks[128 * 128];  // K tile [kv][d]; reused per-wave for P
  __shared__ unsigned short Vs[128 * 128];  // V^T tile [d][sigma(kv)]
  const int t = threadIdx.x, w = t >> 6, l = t & 63;
  const int lr = l & 15, hi = l >> 4;
  const int lkb = hi * 8;
  const int id = blockIdx.x;
  const int pp = id & 255;
  const int bh = pp >> 3, k8 = pp & 7;
  const int qt = (id < 256) ? (15 - k8) : k8;
  const int b = bh >> 4, h = bh & 15;
  const int q0 = qt * 128;

  bf16x8 qf[2][4];
#pragma unroll
  for (int mi = 0; mi < 2; ++mi)
#pragma unroll
    for (int kk = 0; kk < 4; ++kk) {
      const uint4* p = reinterpret_cast<const uint4*>(
          Qb + (size_t)(b * SQ + q0 + w * 32 + mi * 16 + lr) * DM + h * HD + kk * 32 + lkb);
      qf[mi][kk] = __builtin_bit_cast(bf16x8, *p);
    }
  f32x4 o[2][8] = {};
  float mrun[2][4], lrun[2][4];
#pragma unroll
  for (int mi = 0; mi < 2; ++mi)
#pragma unroll
    for (int j = 0; j < 4; ++j) { mrun[mi][j] = -3.0e38f; lrun[mi][j] = 0.f; }

  for (int kt = 0; kt <= qt; ++kt) {
    const bool diag = (kt == qt);
    const int nlim = diag ? 2 * w + 2 : 8;  // QK frags fully above diagonal skipped
    const unsigned short* Kg = Kc + (size_t)(b * SQ + kt * 128) * HD;
    const unsigned short* Vg = Vt + (size_t)b * HD * SQ + kt * 128;
#pragma unroll
    for (int p = 0; p < 8; ++p) {
      int seg = p * 256 + t;
      int row = seg >> 4, sl = seg & 15;
      int slx = sl ^ swz(row);  // pre-swizzled source column (16B units)
      gload16(Kg + (size_t)row * HD + slx * 8, (void*)(Ks + seg * 8));
      gload16(Vg + (size_t)row * SQ + slx * 8, (void*)(Vs + seg * 8));
    }
    __syncthreads();

    f32x4 s[2][8] = {};
#pragma unroll
    for (int kk = 0; kk < 4; ++kk) {
      bf16x8 kf[8];
#pragma unroll
      for (int ni = 0; ni < 8; ++ni)
        if (ni < nlim) {
          int r = ni * 16 + lr;
          kf[ni] = *reinterpret_cast<const bf16x8*>(
              Ks + r * 128 + (((kk * 4 + hi) ^ swz(r)) << 3));
        }
#pragma unroll
      for (int mi = 0; mi < 2; ++mi)
#pragma unroll
        for (int ni = 0; ni < 8; ++ni)
          if (ni < nlim)
            s[mi][ni] = __builtin_amdgcn_mfma_f32_16x16x32_bf16(qf[mi][kk], kf[ni], s[mi][ni], 0, 0, 0);
    }

    if (diag) {  // causal mask (also overwrites the skipped garbage frags)
#pragma unroll
      for (int mi = 0; mi < 2; ++mi)
#pragma unroll
        for (int ni = 0; ni < 8; ++ni)
#pragma unroll
          for (int j = 0; j < 4; ++j) {
            int rq = w * 32 + mi * 16 + hi * 4 + j;
            int ck = ni * 16 + lr;
            if (ck > rq) s[mi][ni][j] = -3.0e38f;
          }
    }

#pragma unroll
    for (int mi = 0; mi < 2; ++mi) {
#pragma unroll
      for (int j = 0; j < 4; ++j) {
        float pm = s[mi][0][j];
#pragma unroll
        for (int ni = 1; ni < 8; ++ni) pm = fmaxf(pm, s[mi][ni][j]);
#pragma unroll
        for (int dd = 1; dd < 16; dd <<= 1) pm = fmaxf(pm, __shfl_xor(pm, dd));
        if (pm > mrun[mi][j]) {  // exact rescale-skip
          float sc = __builtin_amdgcn_exp2f(mrun[mi][j] - pm);
          mrun[mi][j] = pm;
          lrun[mi][j] *= sc;
#pragma unroll
          for (int ni = 0; ni < 8; ++ni) o[mi][ni][j] *= sc;
        }
        float mnew = mrun[mi][j];
        float rs = 0.f;
#pragma unroll
        for (int ni = 0; ni < 8; ++ni) {
          float pv = __builtin_amdgcn_exp2f(s[mi][ni][j] - mnew);
          s[mi][ni][j] = pv;
          rs += pv;
        }
#pragma unroll
        for (int dd = 1; dd < 16; dd <<= 1) rs += __shfl_xor(rs, dd);
        lrun[mi][j] += rs;
      }
    }

    __syncthreads();  // all waves done reading K frags -> safe to overlay P
    unsigned short* Ps = Ks + w * 32 * 128;
#pragma unroll
    for (int mi = 0; mi < 2; ++mi)
#pragma unroll
      for (int j = 0; j < 4; ++j) {
        int prow = mi * 16 + hi * 4 + j;
        unsigned short pk[8];
#pragma unroll
        for (int ni = 0; ni < 8; ++ni) pk[ni] = f2bf(s[mi][ni][j]);
        // sigma: value at natural kv-col ni*16+lr -> position lr*8+ni (slot lr)
        *reinterpret_cast<uint4*>(Ps + prow * 128 + ((lr ^ swz(prow)) << 3)) =
            *reinterpret_cast<const uint4*>(pk);
      }

#pragma unroll
    for (int kk = 0; kk < 4; ++kk) {
      bf16x8 pa[2], vf[8];
#pragma unroll
      for (int mi = 0; mi < 2; ++mi) {
        int r = mi * 16 + lr;
        pa[mi] = *reinterpret_cast<const bf16x8*>(
            Ps + r * 128 + (((kk * 4 + hi) ^ swz(r)) << 3));
      }
#pragma unroll
      for (int ni = 0; ni < 8; ++ni) {
        int r = ni * 16 + lr;
        vf[ni] = *reinterpret_cast<const bf16x8*>(
            Vs + r * 128 + (((kk * 4 + hi) ^ swz(r)) << 3));
      }
#pragma unroll
      for (int mi = 0; mi < 2; ++mi)
#pragma unroll
        for (int ni = 0; ni < 8; ++ni)
          o[mi][ni] = __builtin_amdgcn_mfma_f32_16x16x32_bf16(pa[mi], vf[ni], o[mi][ni], 0, 0, 0);
    }
    __syncthreads();  // done with Vs / P before next tile's staging
  }

#pragma unroll
  for (int mi = 0; mi < 2; ++mi)
#pragma unroll
    for (int ni = 0; ni < 8; ++ni)
#pragma unroll
      for (int j = 0; j < 4; ++j) {
        int q = q0 + w * 32 + mi * 16 + hi * 4 + j;
        float val = o[mi][ni][j] / lrun[mi][j];
        Hb[(size_t)(b * SQ + q) * DM + h * HD + ni * 16 + lr] = f2bf(val);
      }
}

extern "C" void kernel_launch(void* const* d_in, const int* in_sizes, int n_in,
                              void* d_out, int out_size, void* d_ws, size_t ws_size,
                              hipStream_t stream) {
  const float* X   = (const float*)d_in[0];
  const float* Wq  = (const float*)d_in[1];
  const float* Wkv = (const float*)d_in[2];
  const float* Wo  = (const float*)d_in[3];
  char* ws = (char*)d_ws;
  // ws layout (bytes)
  unsigned short* Xb    = (unsigned short*)(ws + 0);           // 16 MB
  unsigned short* Wqkvb = (unsigned short*)(ws + 16777216);    // 9 MB [2304][2048]
  unsigned short* Wob   = (unsigned short*)(ws + 26214400);    // 8 MB
  unsigned short* Qb    = (unsigned short*)(ws + 34603008);    // 16 MB
  unsigned short* Kc    = (unsigned short*)(ws + 51380224);    // 1 MB
  unsigned short* Vt    = (unsigned short*)(ws + 52428800);    // 1 MB
  unsigned short* Hb    = (unsigned short*)(ws + 53477376);    // 16 MB

  cast_f32_to_bf16<<<2048, 256, 0, stream>>>(X, Xb, NB * SQ * DM);
  cast_weights<<<2048, 256, 0, stream>>>(Wq, Wkv, Wo, Wqkvb, Wob);

  // [Q | K | V] = X [Wq;Wkv]^T fused: Q scaled by log2e/sqrt(HD) -> Qb,
  // K -> Kc [b][s][128], V -> Vt [b][d][sigma(s)]
  gemm_bt<2><<<dim3(32, 18), 256, 0, stream>>>(Xb, Wqkvb, Qb, Kc, Vt,
                                               NB * SQ, DM + 2 * HD, DM,
                                               0.1275174293f);
  // attention -> Hb [b][s][h*128+d]
  mqa_attn<<<512, 256, 0, stream>>>(Qb, Kc, Vt, Hb);
  // out = Hb Wo^T, f32
  gemm_bt<1><<<dim3(32, 16), 256, 0, stream>>>(Hb, Wob, d_out, nullptr, nullptr,
                                               NB * SQ, DM, DM, 1.0f);
}

// Round 10
// 312.471 us; speedup vs baseline: 1.3053x; 1.0876x over previous
//
#include <hip/hip_runtime.h>
#include <hip/hip_bf16.h>
#include <stdint.h>

#define DM 2048
#define NH 16
#define HD 128
#define NB 2
#define SQ 2048

typedef __bf16 bf16x8 __attribute__((ext_vector_type(8)));
typedef float f32x4 __attribute__((ext_vector_type(4)));

typedef __attribute__((address_space(1))) uint32_t as1_u32;
typedef __attribute__((address_space(3))) uint32_t as3_u32;

__device__ __forceinline__ void gload16(const void* g, void* l) {
  __builtin_amdgcn_global_load_lds((const as1_u32*)g, (as3_u32*)l, 16, 0, 0);
}

__device__ __forceinline__ unsigned short f2bf(float f) {
  __hip_bfloat16 h = __float2bfloat16(f);
  return __builtin_bit_cast(unsigned short, h);
}

// LDS bank swizzle: 16B-slot XOR for row r.
__device__ __forceinline__ int swz(int r) { return (r ^ (r >> 3)) & 7; }

__global__ void cast_f32_to_bf16(const float* __restrict__ in,
                                 unsigned short* __restrict__ out, int n) {
  int stride = gridDim.x * blockDim.x * 4;
  for (int i = (blockIdx.x * blockDim.x + threadIdx.x) * 4; i < n; i += stride) {
    float4 v = *reinterpret_cast<const float4*>(in + i);
    ushort4 o;
    o.x = f2bf(v.x); o.y = f2bf(v.y); o.z = f2bf(v.z); o.w = f2bf(v.w);
    *reinterpret_cast<ushort4*>(out + i) = o;
  }
}

// Wq (2048x2048) -> Wqkvb rows 0..2047; Wkv (256x2048) -> rows 2048..2303;
// Wo (2048x2048) -> Wob. All contiguous segments.
__global__ void cast_weights(const float* __restrict__ Wq,
                             const float* __restrict__ Wkv,
                             const float* __restrict__ Wo,
                             unsigned short* __restrict__ Wqkvb,
                             unsigned short* __restrict__ Wob) {
  const int n = 4194304 + 524288 + 4194304;
  int stride = gridDim.x * blockDim.x * 4;
  for (int i = (blockIdx.x * blockDim.x + threadIdx.x) * 4; i < n; i += stride) {
    const float* src; unsigned short* dst;
    if (i < 4194304)      { src = Wq + i;            dst = Wqkvb + i; }
    else if (i < 4718592) { src = Wkv + (i - 4194304); dst = Wqkvb + i; }
    else                  { src = Wo + (i - 4718592);  dst = Wob + (i - 4718592); }
    float4 v = *reinterpret_cast<const float4*>(src);
    ushort4 o;
    o.x = f2bf(v.x); o.y = f2bf(v.y); o.z = f2bf(v.z); o.w = f2bf(v.w);
    *reinterpret_cast<ushort4*>(dst) = o;
  }
}

// C = A * B^T. A: M x K bf16 row-major. B: N x K bf16 row-major.
// MODE 1: f32 out (C0, row stride N).
// MODE 2: fused QKV epilogue (N=2304, column-block-aligned routing):
//   cc < 2048          -> Qb[m*2048+cc] = v*scale (bf16)   [scale = log2e/sqrt(HD)]
//   2048 <= cc < 2176  -> Kc[m*128 + cc-2048]
//   cc >= 2176         -> Vt[(b*128 + cc-2176)*2048 + sigma-permuted s]
//   (sigma(c) = (c&15)*8 + (c>>4) within each 128-tile of s; PV is invariant
//    under a shared kv-permutation of P-cols and V-rows.)
template<int MODE>
__global__ void gemm_bt(const unsigned short* __restrict__ A,
                        const unsigned short* __restrict__ Bm,
                        void* __restrict__ C0, void* __restrict__ C1,
                        void* __restrict__ C2,
                        int M, int N, int K, float scale) {
  __shared__ unsigned short As[128 * 32];
  __shared__ unsigned short Bs[128 * 32];
  const int t = threadIdx.x;
  const int w = t >> 6, l = t & 63;
  const int lr = l & 15, lkb = (l >> 4) * 8;
  const int m0 = blockIdx.x * 128, n0 = blockIdx.y * 128;
  const int wr = (w >> 1) * 64, wc = (w & 1) * 64;
  f32x4 acc[4][4] = {};
  for (int k0 = 0; k0 < K; k0 += 32) {
#pragma unroll
    for (int p = 0; p < 2; ++p) {
      int seg = p * 256 + t;
      int row = seg >> 2, c8 = (seg & 3) * 8;
      gload16(A + (size_t)(m0 + row) * K + k0 + c8, (void*)(As + seg * 8));
      gload16(Bm + (size_t)(n0 + row) * K + k0 + c8, (void*)(Bs + seg * 8));
    }
    __syncthreads();
    bf16x8 af[4], bfv[4];
#pragma unroll
    for (int mi = 0; mi < 4; ++mi)
      af[mi] = *reinterpret_cast<const bf16x8*>(As + (wr + mi * 16 + lr) * 32 + lkb);
#pragma unroll
    for (int ni = 0; ni < 4; ++ni)
      bfv[ni] = *reinterpret_cast<const bf16x8*>(Bs + (wc + ni * 16 + lr) * 32 + lkb);
#pragma unroll
    for (int mi = 0; mi < 4; ++mi)
#pragma unroll
      for (int ni = 0; ni < 4; ++ni)
        acc[mi][ni] = __builtin_amdgcn_mfma_f32_16x16x32_bf16(af[mi], bfv[ni], acc[mi][ni], 0, 0, 0);
    __syncthreads();
  }
#pragma unroll
  for (int mi = 0; mi < 4; ++mi) {
#pragma unroll
    for (int ni = 0; ni < 4; ++ni) {
      const int r0 = m0 + wr + mi * 16 + (l >> 4) * 4;
      const int cc = n0 + wc + ni * 16 + lr;
#pragma unroll
      for (int j = 0; j < 4; ++j) {
        float v = acc[mi][ni][j];
        if (MODE == 1) {
          ((float*)C0)[(size_t)(r0 + j) * N + cc] = v;
        } else {
          int m = r0 + j;
          if (cc < DM) {
            ((unsigned short*)C0)[(size_t)m * DM + cc] = f2bf(v * scale);
          } else if (cc < DM + HD) {
            ((unsigned short*)C1)[(size_t)m * HD + (cc - DM)] = f2bf(v);
          } else {
            int b = m >> 11, s = m & (SQ - 1);
            int c = s & 127;
            int sp = (s & ~127) + ((c & 15) * 8 + (c >> 4));
            ((unsigned short*)C2)[((size_t)b * HD + (cc - DM - HD)) * SQ + sp] = f2bf(v);
          }
        }
      }
    }
  }
}

// Flash attention, MQA. Qb: [4096][2048] bf16, pre-scaled by log2e/sqrt(128)
// (softmax in exp2 domain). Kc: [b][s][128] bf16. Vt: [b][d][sigma(s)] bf16.
// Hb out: [b][s][h*128+d] bf16.
// Block: 256 thr (4 waves x 32 q-rows). KV tile = 128, STAGED in LDS via
// global_load_lds. 16B slots XOR-swizzled with swz(row), staged via
// pre-swizzled GLOBAL source column (both-sides involution).
// P overlays the K region per-wave after the QK barrier, sigma-packed b128.
// NO per-fragment diagonal skip: round-9 showed the `if(ni<nlim)` guards
// fragment the QK inner loop's scheduling (MfmaUtil 13.2->10.5, dur +23%)
// — branches in all 136 tiles cost far more than skipping ~3% of MFMAs on
// the 16 diagonal tiles. Mask-only diagonal handling (round-3 structure).
// Grid: 1D 512; id and id+256 carry complementary qt for CU load balance.
__global__ __launch_bounds__(256) void mqa_attn(const unsigned short* __restrict__ Qb,
                                                const unsigned short* __restrict__ Kc,
                                                const unsigned short* __restrict__ Vt,
                                                unsigned short* __restrict__ Hb) {
  __shared__ unsigned short Ks[128 * 128];  // K tile [kv][d]; reused per-wave for P
  __shared__ unsigned short Vs[128 * 128];  // V^T tile [d][sigma(kv)]
  const int t = threadIdx.x, w = t >> 6, l = t & 63;
  const int lr = l & 15, hi = l >> 4;
  const int lkb = hi * 8;
  const int id = blockIdx.x;
  const int pp = id & 255;
  const int bh = pp >> 3, k8 = pp & 7;
  const int qt = (id < 256) ? (15 - k8) : k8;
  const int b = bh >> 4, h = bh & 15;
  const int q0 = qt * 128;

  bf16x8 qf[2][4];
#pragma unroll
  for (int mi = 0; mi < 2; ++mi)
#pragma unroll
    for (int kk = 0; kk < 4; ++kk) {
      const uint4* p = reinterpret_cast<const uint4*>(
          Qb + (size_t)(b * SQ + q0 + w * 32 + mi * 16 + lr) * DM + h * HD + kk * 32 + lkb);
      qf[mi][kk] = __builtin_bit_cast(bf16x8, *p);
    }
  f32x4 o[2][8] = {};
  float mrun[2][4], lrun[2][4];
#pragma unroll
  for (int mi = 0; mi < 2; ++mi)
#pragma unroll
    for (int j = 0; j < 4; ++j) { mrun[mi][j] = -3.0e38f; lrun[mi][j] = 0.f; }

  for (int kt = 0; kt <= qt; ++kt) {
    const unsigned short* Kg = Kc + (size_t)(b * SQ + kt * 128) * HD;
    const unsigned short* Vg = Vt + (size_t)b * HD * SQ + kt * 128;
#pragma unroll
    for (int p = 0; p < 8; ++p) {
      int seg = p * 256 + t;
      int row = seg >> 4, sl = seg & 15;
      int slx = sl ^ swz(row);  // pre-swizzled source column (16B units)
      gload16(Kg + (size_t)row * HD + slx * 8, (void*)(Ks + seg * 8));
      gload16(Vg + (size_t)row * SQ + slx * 8, (void*)(Vs + seg * 8));
    }
    __syncthreads();

    f32x4 s[2][8] = {};
#pragma unroll
    for (int kk = 0; kk < 4; ++kk) {
      bf16x8 kf[8];
#pragma unroll
      for (int ni = 0; ni < 8; ++ni) {
        int r = ni * 16 + lr;
        kf[ni] = *reinterpret_cast<const bf16x8*>(
            Ks + r * 128 + (((kk * 4 + hi) ^ swz(r)) << 3));
      }
#pragma unroll
      for (int mi = 0; mi < 2; ++mi)
#pragma unroll
        for (int ni = 0; ni < 8; ++ni)
          s[mi][ni] = __builtin_amdgcn_mfma_f32_16x16x32_bf16(qf[mi][kk], kf[ni], s[mi][ni], 0, 0, 0);
    }

    if (kt == qt) {  // causal mask on the diagonal tile
#pragma unroll
      for (int mi = 0; mi < 2; ++mi)
#pragma unroll
        for (int ni = 0; ni < 8; ++ni)
#pragma unroll
          for (int j = 0; j < 4; ++j) {
            int rq = w * 32 + mi * 16 + hi * 4 + j;
            int ck = ni * 16 + lr;
            if (ck > rq) s[mi][ni][j] = -3.0e38f;
          }
    }

#pragma unroll
    for (int mi = 0; mi < 2; ++mi) {
#pragma unroll
      for (int j = 0; j < 4; ++j) {
        float pm = s[mi][0][j];
#pragma unroll
        for (int ni = 1; ni < 8; ++ni) pm = fmaxf(pm, s[mi][ni][j]);
#pragma unroll
        for (int dd = 1; dd < 16; dd <<= 1) pm = fmaxf(pm, __shfl_xor(pm, dd));
        if (pm > mrun[mi][j]) {  // exact rescale-skip
          float sc = __builtin_amdgcn_exp2f(mrun[mi][j] - pm);
          mrun[mi][j] = pm;
          lrun[mi][j] *= sc;
#pragma unroll
          for (int ni = 0; ni < 8; ++ni) o[mi][ni][j] *= sc;
        }
        float mnew = mrun[mi][j];
        float rs = 0.f;
#pragma unroll
        for (int ni = 0; ni < 8; ++ni) {
          float pv = __builtin_amdgcn_exp2f(s[mi][ni][j] - mnew);
          s[mi][ni][j] = pv;
          rs += pv;
        }
#pragma unroll
        for (int dd = 1; dd < 16; dd <<= 1) rs += __shfl_xor(rs, dd);
        lrun[mi][j] += rs;
      }
    }

    __syncthreads();  // all waves done reading K frags -> safe to overlay P
    unsigned short* Ps = Ks + w * 32 * 128;
#pragma unroll
    for (int mi = 0; mi < 2; ++mi)
#pragma unroll
      for (int j = 0; j < 4; ++j) {
        int prow = mi * 16 + hi * 4 + j;
        unsigned short pk[8];
#pragma unroll
        for (int ni = 0; ni < 8; ++ni) pk[ni] = f2bf(s[mi][ni][j]);
        // sigma: value at natural kv-col ni*16+lr -> position lr*8+ni (slot lr)
        *reinterpret_cast<uint4*>(Ps + prow * 128 + ((lr ^ swz(prow)) << 3)) =
            *reinterpret_cast<const uint4*>(pk);
      }

#pragma unroll
    for (int kk = 0; kk < 4; ++kk) {
      bf16x8 pa[2], vf[8];
#pragma unroll
      for (int mi = 0; mi < 2; ++mi) {
        int r = mi * 16 + lr;
        pa[mi] = *reinterpret_cast<const bf16x8*>(
            Ps + r * 128 + (((kk * 4 + hi) ^ swz(r)) << 3));
      }
#pragma unroll
      for (int ni = 0; ni < 8; ++ni) {
        int r = ni * 16 + lr;
        vf[ni] = *reinterpret_cast<const bf16x8*>(
            Vs + r * 128 + (((kk * 4 + hi) ^ swz(r)) << 3));
      }
#pragma unroll
      for (int mi = 0; mi < 2; ++mi)
#pragma unroll
        for (int ni = 0; ni < 8; ++ni)
          o[mi][ni] = __builtin_amdgcn_mfma_f32_16x16x32_bf16(pa[mi], vf[ni], o[mi][ni], 0, 0, 0);
    }
    __syncthreads();  // done with Vs / P before next tile's staging
  }

#pragma unroll
  for (int mi = 0; mi < 2; ++mi)
#pragma unroll
    for (int ni = 0; ni < 8; ++ni)
#pragma unroll
      for (int j = 0; j < 4; ++j) {
        int q = q0 + w * 32 + mi * 16 + hi * 4 + j;
        float val = o[mi][ni][j] / lrun[mi][j];
        Hb[(size_t)(b * SQ + q) * DM + h * HD + ni * 16 + lr] = f2bf(val);
      }
}

extern "C" void kernel_launch(void* const* d_in, const int* in_sizes, int n_in,
                              void* d_out, int out_size, void* d_ws, size_t ws_size,
                              hipStream_t stream) {
  const float* X   = (const float*)d_in[0];
  const float* Wq  = (const float*)d_in[1];
  const float* Wkv = (const float*)d_in[2];
  const float* Wo  = (const float*)d_in[3];
  char* ws = (char*)d_ws;
  // ws layout (bytes)
  unsigned short* Xb    = (unsigned short*)(ws + 0);           // 16 MB
  unsigned short* Wqkvb = (unsigned short*)(ws + 16777216);    // 9 MB [2304][2048]
  unsigned short* Wob   = (unsigned short*)(ws + 26214400);    // 8 MB
  unsigned short* Qb    = (unsigned short*)(ws + 34603008);    // 16 MB
  unsigned short* Kc    = (unsigned short*)(ws + 51380224);    // 1 MB
  unsigned short* Vt    = (unsigned short*)(ws + 52428800);    // 1 MB
  unsigned short* Hb    = (unsigned short*)(ws + 53477376);    // 16 MB

  cast_f32_to_bf16<<<2048, 256, 0, stream>>>(X, Xb, NB * SQ * DM);
  cast_weights<<<2048, 256, 0, stream>>>(Wq, Wkv, Wo, Wqkvb, Wob);

  // [Q | K | V] = X [Wq;Wkv]^T fused: Q scaled by log2e/sqrt(HD) -> Qb,
  // K -> Kc [b][s][128], V -> Vt [b][d][sigma(s)]
  gemm_bt<2><<<dim3(32, 18), 256, 0, stream>>>(Xb, Wqkvb, Qb, Kc, Vt,
                                               NB * SQ, DM + 2 * HD, DM,
                                               0.1275174293f);
  // attention -> Hb [b][s][h*128+d]
  mqa_attn<<<512, 256, 0, stream>>>(Qb, Kc, Vt, Hb);
  // out = Hb Wo^T, f32
  gemm_bt<1><<<dim3(32, 16), 256, 0, stream>>>(Hb, Wob, d_out, nullptr, nullptr,
                                               NB * SQ, DM, DM, 1.0f);
}

// Round 11
// 310.460 us; speedup vs baseline: 1.3137x; 1.0065x over previous
//
#include <hip/hip_runtime.h>
#include <hip/hip_bf16.h>
#include <stdint.h>

#define DM 2048
#define NH 16
#define HD 128
#define NB 2
#define SQ 2048

typedef __bf16 bf16x8 __attribute__((ext_vector_type(8)));
typedef float f32x4 __attribute__((ext_vector_type(4)));

typedef __attribute__((address_space(1))) uint32_t as1_u32;
typedef __attribute__((address_space(3))) uint32_t as3_u32;

__device__ __forceinline__ void gload16(const void* g, void* l) {
  __builtin_amdgcn_global_load_lds((const as1_u32*)g, (as3_u32*)l, 16, 0, 0);
}

__device__ __forceinline__ unsigned short f2bf(float f) {
  __hip_bfloat16 h = __float2bfloat16(f);
  return __builtin_bit_cast(unsigned short, h);
}

// LDS bank swizzle: 16B-slot XOR for row r.
__device__ __forceinline__ int swz(int r) { return (r ^ (r >> 3)) & 7; }

__global__ void cast_f32_to_bf16(const float* __restrict__ in,
                                 unsigned short* __restrict__ out, int n) {
  int stride = gridDim.x * blockDim.x * 4;
  for (int i = (blockIdx.x * blockDim.x + threadIdx.x) * 4; i < n; i += stride) {
    float4 v = *reinterpret_cast<const float4*>(in + i);
    ushort4 o;
    o.x = f2bf(v.x); o.y = f2bf(v.y); o.z = f2bf(v.z); o.w = f2bf(v.w);
    *reinterpret_cast<ushort4*>(out + i) = o;
  }
}

// Wq (2048x2048) -> Wqkvb rows 0..2047; Wkv (256x2048) -> rows 2048..2303;
// Wo (2048x2048) -> Wob. All contiguous segments.
__global__ void cast_weights(const float* __restrict__ Wq,
                             const float* __restrict__ Wkv,
                             const float* __restrict__ Wo,
                             unsigned short* __restrict__ Wqkvb,
                             unsigned short* __restrict__ Wob) {
  const int n = 4194304 + 524288 + 4194304;
  int stride = gridDim.x * blockDim.x * 4;
  for (int i = (blockIdx.x * blockDim.x + threadIdx.x) * 4; i < n; i += stride) {
    const float* src; unsigned short* dst;
    if (i < 4194304)      { src = Wq + i;            dst = Wqkvb + i; }
    else if (i < 4718592) { src = Wkv + (i - 4194304); dst = Wqkvb + i; }
    else                  { src = Wo + (i - 4718592);  dst = Wob + (i - 4718592); }
    float4 v = *reinterpret_cast<const float4*>(src);
    ushort4 o;
    o.x = f2bf(v.x); o.y = f2bf(v.y); o.z = f2bf(v.z); o.w = f2bf(v.w);
    *reinterpret_cast<ushort4*>(dst) = o;
  }
}

// C = A * B^T. A: M x K bf16 row-major. B: N x K bf16 row-major.
// T3 "minimum 2-phase" pipeline (low-occupancy regime: 2.25 blocks/CU so
// inter-block overlap can't hide the staging drain): double-buffered LDS,
// STAGE(next) issued BEFORE compute(cur), ONE __syncthreads per K-step.
// The barrier's vmcnt(0) then drains loads that aged through the whole
// MFMA phase -> cheap; and one barrier/iter is removed vs the m97 form.
// MODE 1: f32 out (C0, row stride N).
// MODE 2: fused QKV epilogue (N=2304, column-block-aligned routing):
//   cc < 2048          -> Qb[m*2048+cc] = v*scale (bf16)   [scale = log2e/sqrt(HD)]
//   2048 <= cc < 2176  -> Kc[m*128 + cc-2048]
//   cc >= 2176         -> Vt[(b*128 + cc-2176)*2048 + sigma-permuted s]
template<int MODE>
__global__ void gemm_bt(const unsigned short* __restrict__ A,
                        const unsigned short* __restrict__ Bm,
                        void* __restrict__ C0, void* __restrict__ C1,
                        void* __restrict__ C2,
                        int M, int N, int K, float scale) {
  __shared__ unsigned short As[2][128 * 32];
  __shared__ unsigned short Bs[2][128 * 32];
  const int t = threadIdx.x;
  const int w = t >> 6, l = t & 63;
  const int lr = l & 15, lkb = (l >> 4) * 8;
  const int m0 = blockIdx.x * 128, n0 = blockIdx.y * 128;
  const int wr = (w >> 1) * 64, wc = (w & 1) * 64;
  const int srow = t >> 2, sc8 = (t & 3) * 8;  // staging coords (seg = p*256+t)
  f32x4 acc[4][4] = {};

#define STAGE(buf, k0)                                                        \
  {                                                                           \
    gload16(A + (size_t)(m0 + srow) * K + (k0) + sc8,                         \
            (void*)(As[buf] + t * 8));                                        \
    gload16(Bm + (size_t)(n0 + srow) * K + (k0) + sc8,                        \
            (void*)(Bs[buf] + t * 8));                                        \
    gload16(A + (size_t)(m0 + 64 + srow) * K + (k0) + sc8,                    \
            (void*)(As[buf] + 2048 + t * 8));                                 \
    gload16(Bm + (size_t)(n0 + 64 + srow) * K + (k0) + sc8,                   \
            (void*)(Bs[buf] + 2048 + t * 8));                                 \
  }

#define COMPUTE(buf)                                                          \
  {                                                                           \
    bf16x8 af[4], bfv[4];                                                     \
    _Pragma("unroll")                                                         \
    for (int mi = 0; mi < 4; ++mi)                                            \
      af[mi] = *reinterpret_cast<const bf16x8*>(                              \
          As[buf] + (wr + mi * 16 + lr) * 32 + lkb);                          \
    _Pragma("unroll")                                                         \
    for (int ni = 0; ni < 4; ++ni)                                            \
      bfv[ni] = *reinterpret_cast<const bf16x8*>(                             \
          Bs[buf] + (wc + ni * 16 + lr) * 32 + lkb);                          \
    _Pragma("unroll")                                                         \
    for (int mi = 0; mi < 4; ++mi)                                            \
      _Pragma("unroll")                                                       \
      for (int ni = 0; ni < 4; ++ni)                                          \
        acc[mi][ni] = __builtin_amdgcn_mfma_f32_16x16x32_bf16(                \
            af[mi], bfv[ni], acc[mi][ni], 0, 0, 0);                           \
  }

  STAGE(0, 0);
  __syncthreads();
  int cur = 0;
  for (int k0 = 32; k0 < K; k0 += 32) {
    STAGE(cur ^ 1, k0);   // issue next tile's loads first (hide under compute)
    COMPUTE(cur);
    __syncthreads();      // drains this iter's (aged) loads + readers done
    cur ^= 1;
  }
  COMPUTE(cur);
#undef STAGE
#undef COMPUTE

#pragma unroll
  for (int mi = 0; mi < 4; ++mi) {
#pragma unroll
    for (int ni = 0; ni < 4; ++ni) {
      const int r0 = m0 + wr + mi * 16 + (l >> 4) * 4;
      const int cc = n0 + wc + ni * 16 + lr;
#pragma unroll
      for (int j = 0; j < 4; ++j) {
        float v = acc[mi][ni][j];
        if (MODE == 1) {
          ((float*)C0)[(size_t)(r0 + j) * N + cc] = v;
        } else {
          int m = r0 + j;
          if (cc < DM) {
            ((unsigned short*)C0)[(size_t)m * DM + cc] = f2bf(v * scale);
          } else if (cc < DM + HD) {
            ((unsigned short*)C1)[(size_t)m * HD + (cc - DM)] = f2bf(v);
          } else {
            int b = m >> 11, s = m & (SQ - 1);
            int c = s & 127;
            int sp = (s & ~127) + ((c & 15) * 8 + (c >> 4));
            ((unsigned short*)C2)[((size_t)b * HD + (cc - DM - HD)) * SQ + sp] = f2bf(v);
          }
        }
      }
    }
  }
}

// Flash attention, MQA. Qb: [4096][2048] bf16, pre-scaled by log2e/sqrt(128)
// (softmax in exp2 domain). Kc: [b][s][128] bf16. Vt: [b][d][sigma(s)] bf16.
// Hb out: [b][s][h*128+d] bf16.
// Block: 256 thr (4 waves x 32 q-rows). KV tile = 128, STAGED in LDS via
// global_load_lds. 16B slots XOR-swizzled with swz(row), staged via
// pre-swizzled GLOBAL source column (both-sides involution).
// P overlays the K region per-wave after the QK barrier, sigma-packed b128.
// No per-fragment diagonal skip (round-9: branches fragment scheduling).
// Grid: 1D 512; id and id+256 carry complementary qt for CU load balance.
__global__ __launch_bounds__(256) void mqa_attn(const unsigned short* __restrict__ Qb,
                                                const unsigned short* __restrict__ Kc,
                                                const unsigned short* __restrict__ Vt,
                                                unsigned short* __restrict__ Hb) {
  __shared__ unsigned short Ks[128 * 128];  // K tile [kv][d]; reused per-wave for P
  __shared__ unsigned short Vs[128 * 128];  // V^T tile [d][sigma(kv)]
  const int t = threadIdx.x, w = t >> 6, l = t & 63;
  const int lr = l & 15, hi = l >> 4;
  const int lkb = hi * 8;
  const int id = blockIdx.x;
  const int pp = id & 255;
  const int bh = pp >> 3, k8 = pp & 7;
  const int qt = (id < 256) ? (15 - k8) : k8;
  const int b = bh >> 4, h = bh & 15;
  const int q0 = qt * 128;

  bf16x8 qf[2][4];
#pragma unroll
  for (int mi = 0; mi < 2; ++mi)
#pragma unroll
    for (int kk = 0; kk < 4; ++kk) {
      const uint4* p = reinterpret_cast<const uint4*>(
          Qb + (size_t)(b * SQ + q0 + w * 32 + mi * 16 + lr) * DM + h * HD + kk * 32 + lkb);
      qf[mi][kk] = __builtin_bit_cast(bf16x8, *p);
    }
  f32x4 o[2][8] = {};
  float mrun[2][4], lrun[2][4];
#pragma unroll
  for (int mi = 0; mi < 2; ++mi)
#pragma unroll
    for (int j = 0; j < 4; ++j) { mrun[mi][j] = -3.0e38f; lrun[mi][j] = 0.f; }

  for (int kt = 0; kt <= qt; ++kt) {
    const unsigned short* Kg = Kc + (size_t)(b * SQ + kt * 128) * HD;
    const unsigned short* Vg = Vt + (size_t)b * HD * SQ + kt * 128;
#pragma unroll
    for (int p = 0; p < 8; ++p) {
      int seg = p * 256 + t;
      int row = seg >> 4, sl = seg & 15;
      int slx = sl ^ swz(row);  // pre-swizzled source column (16B units)
      gload16(Kg + (size_t)row * HD + slx * 8, (void*)(Ks + seg * 8));
      gload16(Vg + (size_t)row * SQ + slx * 8, (void*)(Vs + seg * 8));
    }
    __syncthreads();

    f32x4 s[2][8] = {};
#pragma unroll
    for (int kk = 0; kk < 4; ++kk) {
      bf16x8 kf[8];
#pragma unroll
      for (int ni = 0; ni < 8; ++ni) {
        int r = ni * 16 + lr;
        kf[ni] = *reinterpret_cast<const bf16x8*>(
            Ks + r * 128 + (((kk * 4 + hi) ^ swz(r)) << 3));
      }
#pragma unroll
      for (int mi = 0; mi < 2; ++mi)
#pragma unroll
        for (int ni = 0; ni < 8; ++ni)
          s[mi][ni] = __builtin_amdgcn_mfma_f32_16x16x32_bf16(qf[mi][kk], kf[ni], s[mi][ni], 0, 0, 0);
    }

    if (kt == qt) {  // causal mask on the diagonal tile
#pragma unroll
      for (int mi = 0; mi < 2; ++mi)
#pragma unroll
        for (int ni = 0; ni < 8; ++ni)
#pragma unroll
          for (int j = 0; j < 4; ++j) {
            int rq = w * 32 + mi * 16 + hi * 4 + j;
            int ck = ni * 16 + lr;
            if (ck > rq) s[mi][ni][j] = -3.0e38f;
          }
    }

#pragma unroll
    for (int mi = 0; mi < 2; ++mi) {
#pragma unroll
      for (int j = 0; j < 4; ++j) {
        float pm = s[mi][0][j];
#pragma unroll
        for (int ni = 1; ni < 8; ++ni) pm = fmaxf(pm, s[mi][ni][j]);
#pragma unroll
        for (int dd = 1; dd < 16; dd <<= 1) pm = fmaxf(pm, __shfl_xor(pm, dd));
        if (pm > mrun[mi][j]) {  // exact rescale-skip
          float sc = __builtin_amdgcn_exp2f(mrun[mi][j] - pm);
          mrun[mi][j] = pm;
          lrun[mi][j] *= sc;
#pragma unroll
          for (int ni = 0; ni < 8; ++ni) o[mi][ni][j] *= sc;
        }
        float mnew = mrun[mi][j];
        float rs = 0.f;
#pragma unroll
        for (int ni = 0; ni < 8; ++ni) {
          float pv = __builtin_amdgcn_exp2f(s[mi][ni][j] - mnew);
          s[mi][ni][j] = pv;
          rs += pv;
        }
#pragma unroll
        for (int dd = 1; dd < 16; dd <<= 1) rs += __shfl_xor(rs, dd);
        lrun[mi][j] += rs;
      }
    }

    __syncthreads();  // all waves done reading K frags -> safe to overlay P
    unsigned short* Ps = Ks + w * 32 * 128;
#pragma unroll
    for (int mi = 0; mi < 2; ++mi)
#pragma unroll
      for (int j = 0; j < 4; ++j) {
        int prow = mi * 16 + hi * 4 + j;
        unsigned short pk[8];
#pragma unroll
        for (int ni = 0; ni < 8; ++ni) pk[ni] = f2bf(s[mi][ni][j]);
        // sigma: value at natural kv-col ni*16+lr -> position lr*8+ni (slot lr)
        *reinterpret_cast<uint4*>(Ps + prow * 128 + ((lr ^ swz(prow)) << 3)) =
            *reinterpret_cast<const uint4*>(pk);
      }

#pragma unroll
    for (int kk = 0; kk < 4; ++kk) {
      bf16x8 pa[2], vf[8];
#pragma unroll
      for (int mi = 0; mi < 2; ++mi) {
        int r = mi * 16 + lr;
        pa[mi] = *reinterpret_cast<const bf16x8*>(
            Ps + r * 128 + (((kk * 4 + hi) ^ swz(r)) << 3));
      }
#pragma unroll
      for (int ni = 0; ni < 8; ++ni) {
        int r = ni * 16 + lr;
        vf[ni] = *reinterpret_cast<const bf16x8*>(
            Vs + r * 128 + (((kk * 4 + hi) ^ swz(r)) << 3));
      }
#pragma unroll
      for (int mi = 0; mi < 2; ++mi)
#pragma unroll
        for (int ni = 0; ni < 8; ++ni)
          o[mi][ni] = __builtin_amdgcn_mfma_f32_16x16x32_bf16(pa[mi], vf[ni], o[mi][ni], 0, 0, 0);
    }
    __syncthreads();  // done with Vs / P before next tile's staging
  }

#pragma unroll
  for (int mi = 0; mi < 2; ++mi)
#pragma unroll
    for (int ni = 0; ni < 8; ++ni)
#pragma unroll
      for (int j = 0; j < 4; ++j) {
        int q = q0 + w * 32 + mi * 16 + hi * 4 + j;
        float val = o[mi][ni][j] / lrun[mi][j];
        Hb[(size_t)(b * SQ + q) * DM + h * HD + ni * 16 + lr] = f2bf(val);
      }
}

extern "C" void kernel_launch(void* const* d_in, const int* in_sizes, int n_in,
                              void* d_out, int out_size, void* d_ws, size_t ws_size,
                              hipStream_t stream) {
  const float* X   = (const float*)d_in[0];
  const float* Wq  = (const float*)d_in[1];
  const float* Wkv = (const float*)d_in[2];
  const float* Wo  = (const float*)d_in[3];
  char* ws = (char*)d_ws;
  // ws layout (bytes)
  unsigned short* Xb    = (unsigned short*)(ws + 0);           // 16 MB
  unsigned short* Wqkvb = (unsigned short*)(ws + 16777216);    // 9 MB [2304][2048]
  unsigned short* Wob   = (unsigned short*)(ws + 26214400);    // 8 MB
  unsigned short* Qb    = (unsigned short*)(ws + 34603008);    // 16 MB
  unsigned short* Kc    = (unsigned short*)(ws + 51380224);    // 1 MB
  unsigned short* Vt    = (unsigned short*)(ws + 52428800);    // 1 MB
  unsigned short* Hb    = (unsigned short*)(ws + 53477376);    // 16 MB

  cast_f32_to_bf16<<<2048, 256, 0, stream>>>(X, Xb, NB * SQ * DM);
  cast_weights<<<2048, 256, 0, stream>>>(Wq, Wkv, Wo, Wqkvb, Wob);

  // [Q | K | V] = X [Wq;Wkv]^T fused: Q scaled by log2e/sqrt(HD) -> Qb,
  // K -> Kc [b][s][128], V -> Vt [b][d][sigma(s)]
  gemm_bt<2><<<dim3(32, 18), 256, 0, stream>>>(Xb, Wqkvb, Qb, Kc, Vt,
                                               NB * SQ, DM + 2 * HD, DM,
                                               0.1275174293f);
  // attention -> Hb [b][s][h*128+d]
  mqa_attn<<<512, 256, 0, stream>>>(Qb, Kc, Vt, Hb);
  // out = Hb Wo^T, f32
  gemm_bt<1><<<dim3(32, 16), 256, 0, stream>>>(Hb, Wob, d_out, nullptr, nullptr,
                                               NB * SQ, DM, DM, 1.0f);
}